// Round 8
// baseline (448.250 us; speedup 1.0000x reference)
//
#include <hip/hip_runtime.h>
#include <hip/hip_bf16.h>
#include <stdint.h>

#define MDIM 4096
#define NDIM 4096
#define KDIM 4096
#define NT 192   // effective K = 12288 over 3 bf16 segments, BK = 64

typedef float f32x16 __attribute__((ext_vector_type(16)));
typedef short s16x8 __attribute__((ext_vector_type(8)));

__device__ __forceinline__ unsigned short f2bf(float x) {
  uint32_t u = __float_as_uint(x);
  uint32_t r = (u + 0x7fffu + ((u >> 16) & 1u)) >> 16;  // RNE
  return (unsigned short)r;
}
__device__ __forceinline__ float bf2f(unsigned short b) {
  return __uint_as_float(((uint32_t)b) << 16);
}

// ---------------- pre-pass 1: split A -> A_hi, A_lo (bf16 [M][K])
__global__ __launch_bounds__(256) void split_a(const float* __restrict__ A,
                                               unsigned short* __restrict__ hi,
                                               unsigned short* __restrict__ lo) {
  size_t i = ((size_t)blockIdx.x * 256 + threadIdx.x) * 4;
  float4 v = *(const float4*)(A + i);
  ushort4 h, l;
  h.x = f2bf(v.x); l.x = f2bf(v.x - bf2f(h.x));
  h.y = f2bf(v.y); l.y = f2bf(v.y - bf2f(h.y));
  h.z = f2bf(v.z); l.z = f2bf(v.z - bf2f(h.z));
  h.w = f2bf(v.w); l.w = f2bf(v.w - bf2f(h.w));
  *(ushort4*)(hi + i) = h;
  *(ushort4*)(lo + i) = l;
}

// ---------------- pre-pass 2: split + transpose B -> B_hiT, B_loT (bf16 [N][K])
__global__ __launch_bounds__(256) void split_bt(const float* __restrict__ B,
                                                unsigned short* __restrict__ hiT,
                                                unsigned short* __restrict__ loT) {
  __shared__ float tile[32][33];
  int n0 = blockIdx.x * 32, k0 = blockIdx.y * 32;
  int tx = threadIdx.x, ty = threadIdx.y;  // block (32,8)
#pragma unroll
  for (int i = 0; i < 32; i += 8)
    tile[ty + i][tx] = B[(size_t)(k0 + ty + i) * NDIM + n0 + tx];
  __syncthreads();
#pragma unroll
  for (int i = 0; i < 32; i += 8) {
    float x = tile[tx][ty + i];
    unsigned short h = f2bf(x);
    unsigned short l = f2bf(x - bf2f(h));
    size_t o = (size_t)(n0 + ty + i) * KDIM + k0 + tx;
    hiT[o] = h;
    loT[o] = l;
  }
}

// ---------------- main GEMM: 256x256, BK=64, 8 waves (2Mx4N), per-wave 128x64.
// 32x32x16 MFMA. LDS is chunked: chunk(R, s') = 1 KiB holding exactly the 64
// granules one fragment-read needs, at lane*16 -> every ds_read_b128 is a
// CONTIGUOUS 1024B read (same pattern as global_load_lds writes; conflict-free
// by construction). Staging permutes granules via per-lane global source addrs;
// each GLDS fills one chunk. Same 4-phase vmcnt(2) schedule as r6.
//
// LDS map (per ring buf, 32 KiB A at 0 / 32 KiB B at +64 KiB):
//   A chunk(R=0..7, s'=0..1) of ks-half ks at  cb + ks*16384 + (R*2+s')*1024
//   B likewise at +65536.  Granule (row r=0..31, hi=0..1) at offset (hi*32+r)*16.
#define GLDS(gp, lp)                                              \
  __builtin_amdgcn_global_load_lds(                               \
      (const __attribute__((address_space(1))) void*)(gp),        \
      (__attribute__((address_space(3))) void*)(lp), 16, 0, 0)

#define BARRIER() asm volatile("s_barrier" ::: "memory")
#define WAITVM2() asm volatile("s_waitcnt vmcnt(2)" ::: "memory")
#define WAITVM0() asm volatile("s_waitcnt vmcnt(0)" ::: "memory")

// slice s (K=16): soff = (s>>1)*16384 + (s&1)*1024
#define RD_A(dst, cb, soff)                                                      \
  _Pragma("unroll")                                                              \
  for (int m = 0; m < 4; ++m)                                                    \
    dst[m] = *(const s16x8*)(paBase + (cb) + m * 2048 + (soff))
#define RD_B(dst, cb, soff)                                                      \
  _Pragma("unroll")                                                              \
  for (int n = 0; n < 2; ++n)                                                    \
    dst[n] = *(const s16x8*)(pbBase + (cb) + n * 2048 + (soff))

#define MFMA32(AV, BV)                                                           \
  __builtin_amdgcn_s_setprio(1);                                                 \
  _Pragma("unroll")                                                              \
  for (int m = 0; m < 4; ++m) {                                                  \
    _Pragma("unroll")                                                            \
    for (int n = 0; n < 2; ++n)                                                  \
      acc[m][n] =                                                                \
          __builtin_amdgcn_mfma_f32_32x32x16_bf16(AV[m], BV[n], acc[m][n], 0, 0, 0); \
  }                                                                              \
  __builtin_amdgcn_s_setprio(0)

// stage A or B chunks (s'=0,1) of ks-half for tile at running ptr rp
#define STAGE_A(rp, dA, ks)                                                      \
  GLDS((rp) + (ks) * 64,      (dA) + (ks) * 16384 + wv * 2048);                  \
  GLDS((rp) + (ks) * 64 + 32, (dA) + (ks) * 16384 + wv * 2048 + 1024)
#define STAGE_B(rp, dB, ks)                                                      \
  GLDS((rp) + (ks) * 64,      (dB) + (ks) * 16384 + wv * 2048);                  \
  GLDS((rp) + (ks) * 64 + 32, (dB) + (ks) * 16384 + wv * 2048 + 1024)

__global__ __launch_bounds__(512, 2) void gemm_k3(
    const unsigned short* __restrict__ Ah, const unsigned short* __restrict__ Al,
    const unsigned short* __restrict__ BhT, const unsigned short* __restrict__ BlT,
    float* __restrict__ C) {
  __shared__ __align__(16) char lds_[131072];  // 128 KiB

  const int tid = threadIdx.x;
  const int l   = tid & 63;
  const int wv  = tid >> 6;   // 0..7
  const int wm  = wv >> 2;    // 0..1
  const int wn  = wv & 3;     // 0..3
  const int fr32 = l & 31;
  const int hi32 = l >> 5;

  // bijective XCD swizzle (256 blocks)
  const int bid = blockIdx.x;
  const int swz = (bid & 7) * 32 + (bid >> 3);
  const int bm = swz >> 4, bn = swz & 15;

  // staging lane source offset: row (wv*32 + fr32), k-granule hi32 (bytes)
  const size_t src_lane = (size_t)(wv * 32 + fr32) * 8192 + hi32 * 16;

  // lane-linear read bases
  const char* paBase = lds_ + wm * 8192 + l * 16;
  const char* pbBase = lds_ + 65536 + wn * 4096 + l * 16;

  const char* cAh = (const char*)Ah;
  const char* cAl = (const char*)Al;
  const char* cBh = (const char*)BhT;
  const char* cBl = (const char*)BlT;
  const size_t aoff = (size_t)(bm * 256) * 8192;
  const size_t boff = (size_t)(bn * 256) * 8192;

  f32x16 acc[4][2] = {};
  s16x8 aX[4], aY[4], bX[2], bY[2];

  // ---- prologue: stage tile 0 fully (A0,B0,A1,B1), drain, read slice0 ----
  {
    const char* rA = cAh + aoff + src_lane;
    const char* rB = cBh + boff + src_lane;
    char* dA = lds_;
    char* dB = lds_ + 65536;
    STAGE_A(rA, dA, 0);
    STAGE_B(rB, dB, 0);
    STAGE_A(rA, dA, 1);
    STAGE_B(rB, dB, 1);
  }
  WAITVM0();
  BARRIER();
  RD_A(aX, 0, 0);
  RD_B(bX, 0, 0);

  const char* segAp[3] = {cAh, cAl, cAh};
  const char* segBp[3] = {cBh, cBh, cBl};
  int t = 0;
#pragma unroll 1
  for (int seg = 0; seg < 3; ++seg) {
    // running per-lane source pointers for tile Tn = t+1
    const char* rpA = segAp[seg] + aoff + src_lane + ((seg == 0) ? 128 : 0);
    const char* rpB = segBp[seg] + boff + src_lane + ((seg == 0) ? 128 : 0);
    const int tEnd = 64 * (seg + 1) - 1;  // t runs while Tn < 64*(seg+1)
#pragma unroll 1
    for (; t < tEnd; ++t) {
      const int cb  = (t & 1) * 32768;
      const int cb2 = cb ^ 32768;
      char* dA = lds_ + cb2;
      char* dB = dA + 65536;

      // ---- ph0: read slice1(t) -> Y; stage A-ks0(t+1); MFMA slice0 (X) ----
      RD_A(aY, cb, 1024);
      RD_B(bY, cb, 1024);
      STAGE_A(rpA, dA, 0);
      MFMA32(aX, bX);

      // ---- ph1: drain ks1(t); read slice2(t) -> X; stage B-ks0(t+1); MFMA slice1 (Y)
      WAITVM2();
      BARRIER();
      RD_A(aX, cb, 16384);
      RD_B(bX, cb, 16384);
      STAGE_B(rpB, dB, 0);
      MFMA32(aY, bY);

      // ---- ph2: read slice3(t) -> Y; stage A-ks1(t+1); MFMA slice2 (X) ----
      RD_A(aY, cb, 17408);
      RD_B(bY, cb, 17408);
      STAGE_A(rpA, dA, 1);
      MFMA32(aX, bX);

      // ---- ph3: drain ks0(t+1); read slice0(t+1) from next buf; stage B-ks1(t+1); MFMA slice3 (Y)
      WAITVM2();
      BARRIER();
      RD_A(aX, cb2, 0);
      RD_B(bX, cb2, 0);
      STAGE_B(rpB, dB, 1);
      MFMA32(aY, bY);

      rpA += 128;
      rpB += 128;
    }
  }

  // ---- peeled tail: t = NT-1 (no staging, no next-tile reads) ----
  {
    const int cb = ((NT - 1) & 1) * 32768;
    // ph0
    RD_A(aY, cb, 1024);
    RD_B(bY, cb, 1024);
    MFMA32(aX, bX);
    // ph1 — drain this tile's ks1 units
    WAITVM0();
    BARRIER();
    RD_A(aX, cb, 16384);
    RD_B(bX, cb, 16384);
    MFMA32(aY, bY);
    // ph2
    RD_A(aY, cb, 17408);
    RD_B(bY, cb, 17408);
    MFMA32(aX, bX);
    // ph3
    MFMA32(aY, bY);
  }

  // ---- epilogue: 32x32 C/D layout col=lane&31, row=(reg&3)+8*(reg>>2)+4*(lane>>5)
  float* Cp = C + (size_t)(bm * 256 + wm * 128) * NDIM + (bn * 256 + wn * 64);
#pragma unroll
  for (int m = 0; m < 4; ++m)
#pragma unroll
    for (int n = 0; n < 2; ++n)
#pragma unroll
      for (int r = 0; r < 16; ++r) {
        const int row = m * 32 + (r & 3) + 8 * (r >> 2) + 4 * hi32;
        Cp[(size_t)row * NDIM + n * 32 + fr32] = acc[m][n][r];
      }
}

// ---------------- fallback: plain fp32 tiled GEMM (ws too small) ----------------
__global__ __launch_bounds__(1024) void gemm_fp32_fallback(const float* __restrict__ A,
                                                           const float* __restrict__ B,
                                                           float* __restrict__ C) {
  __shared__ float As[32][33];
  __shared__ float Bs[32][33];
  int tx = threadIdx.x, ty = threadIdx.y;
  int row = blockIdx.y * 32 + ty, colg = blockIdx.x * 32 + tx;
  float acc = 0.f;
  for (int k0 = 0; k0 < KDIM; k0 += 32) {
    As[ty][tx] = A[(size_t)row * KDIM + k0 + tx];
    Bs[ty][tx] = B[(size_t)(k0 + ty) * NDIM + colg];
    __syncthreads();
#pragma unroll 8
    for (int kk = 0; kk < 32; ++kk) acc += As[ty][kk] * Bs[kk][tx];
    __syncthreads();
  }
  C[(size_t)row * NDIM + colg] = acc;
}

extern "C" void kernel_launch(void* const* d_in, const int* in_sizes, int n_in,
                              void* d_out, int out_size, void* d_ws, size_t ws_size,
                              hipStream_t stream) {
  const float* A = (const float*)d_in[0];
  const float* B = (const float*)d_in[1];
  float* C = (float*)d_out;

  const size_t elems = (size_t)MDIM * KDIM;
  const size_t need = 4 * elems * sizeof(unsigned short);  // 128 MB
  if (ws_size < need) {
    gemm_fp32_fallback<<<dim3(NDIM / 32, MDIM / 32), dim3(32, 32), 0, stream>>>(A, B, C);
    return;
  }

  unsigned short* Ah  = (unsigned short*)d_ws;
  unsigned short* Al  = Ah + elems;
  unsigned short* BhT = Al + elems;
  unsigned short* BlT = BhT + elems;

  split_a<<<(int)(elems / (256 * 4)), 256, 0, stream>>>(A, Ah, Al);
  split_bt<<<dim3(NDIM / 32, KDIM / 32), dim3(32, 8), 0, stream>>>(B, BhT, BlT);
  gemm_k3<<<dim3(256), dim3(512), 0, stream>>>(Ah, Al, BhT, BlT, C);
}

// Round 9
// 392.408 us; speedup vs baseline: 1.1423x; 1.1423x over previous
//
#include <hip/hip_runtime.h>
#include <hip/hip_bf16.h>
#include <stdint.h>

#define MDIM 4096
#define NDIM 4096
#define KDIM 4096
#define NT 192   // effective K = 12288 over 3 bf16 segments, BK = 64

typedef float f32x16 __attribute__((ext_vector_type(16)));
typedef short s16x8 __attribute__((ext_vector_type(8)));

__device__ __forceinline__ unsigned short f2bf(float x) {
  uint32_t u = __float_as_uint(x);
  uint32_t r = (u + 0x7fffu + ((u >> 16) & 1u)) >> 16;  // RNE
  return (unsigned short)r;
}
__device__ __forceinline__ float bf2f(unsigned short b) {
  return __uint_as_float(((uint32_t)b) << 16);
}

// ---------------- pre-pass 1: split A -> A_hi, A_lo (bf16 [M][K])
__global__ __launch_bounds__(256) void split_a(const float* __restrict__ A,
                                               unsigned short* __restrict__ hi,
                                               unsigned short* __restrict__ lo) {
  size_t i = ((size_t)blockIdx.x * 256 + threadIdx.x) * 4;
  float4 v = *(const float4*)(A + i);
  ushort4 h, l;
  h.x = f2bf(v.x); l.x = f2bf(v.x - bf2f(h.x));
  h.y = f2bf(v.y); l.y = f2bf(v.y - bf2f(h.y));
  h.z = f2bf(v.z); l.z = f2bf(v.z - bf2f(h.z));
  h.w = f2bf(v.w); l.w = f2bf(v.w - bf2f(h.w));
  *(ushort4*)(hi + i) = h;
  *(ushort4*)(lo + i) = l;
}

// ---------------- pre-pass 2: split + transpose B -> B_hiT, B_loT (bf16 [N][K])
__global__ __launch_bounds__(256) void split_bt(const float* __restrict__ B,
                                                unsigned short* __restrict__ hiT,
                                                unsigned short* __restrict__ loT) {
  __shared__ float tile[32][33];
  int n0 = blockIdx.x * 32, k0 = blockIdx.y * 32;
  int tx = threadIdx.x, ty = threadIdx.y;  // block (32,8)
#pragma unroll
  for (int i = 0; i < 32; i += 8)
    tile[ty + i][tx] = B[(size_t)(k0 + ty + i) * NDIM + n0 + tx];
  __syncthreads();
#pragma unroll
  for (int i = 0; i < 32; i += 8) {
    float x = tile[tx][ty + i];
    unsigned short h = f2bf(x);
    unsigned short l = f2bf(x - bf2f(h));
    size_t o = (size_t)(n0 + ty + i) * KDIM + k0 + tx;
    hiT[o] = h;
    loT[o] = l;
  }
}

// ---------------- main GEMM: 256x256, BK=64, 8 waves (2Mx4N), per-wave 128x64.
// 32x32x16 MFMA. LDS layout: 1 KiB chunk = 16 rows x 4 granules with in-chunk
// slot permutation slot(j,g) = 4j + (g ^ ((j>>1)&3)).
//  - WRITE: each global_load_lds fills one chunk; lanes 4j..4j+3 read row j's 4
//    granules (64B contiguous per row -> r6-class coalescing).
//  - READ: a 32x32 frag (32 rows x 2 granules) spans 2 chunks; lane->bank
//    residues are exactly uniform (8 lanes / 16B group) -> conflict-free.
//  - kappa (K-16 slice within 32-half) read via base XOR 32.
// Schedule identical to r6/r8: 4 phases, 2 barriers + 2 x vmcnt(2) per tile,
// register-fragment pipeline, ring-2 LDS 128 KiB, setprio, XCD swizzle.
#define GLDS(gp, lp)                                              \
  __builtin_amdgcn_global_load_lds(                               \
      (const __attribute__((address_space(1))) void*)(gp),        \
      (__attribute__((address_space(3))) void*)(lp), 16, 0, 0)

#define BARRIER() asm volatile("s_barrier" ::: "memory")
#define WAITVM2() asm volatile("s_waitcnt vmcnt(2)" ::: "memory")
#define WAITVM0() asm volatile("s_waitcnt vmcnt(0)" ::: "memory")

// slice s: base pa0 (s even) / pa1 (s odd), koff = (s>>1)*16384
#define RD_A(dst, base, cb, koff)                                                \
  _Pragma("unroll")                                                              \
  for (int m = 0; m < 4; ++m)                                                    \
    dst[m] = *(const s16x8*)((base) + (cb) + (koff) + m * 2048)
#define RD_B(dst, base, cb, koff)                                                \
  _Pragma("unroll")                                                              \
  for (int n = 0; n < 2; ++n)                                                    \
    dst[n] = *(const s16x8*)((base) + (cb) + (koff) + n * 2048)

#define MFMA32(AV, BV)                                                           \
  __builtin_amdgcn_s_setprio(1);                                                 \
  _Pragma("unroll")                                                              \
  for (int m = 0; m < 4; ++m) {                                                  \
    _Pragma("unroll")                                                            \
    for (int n = 0; n < 2; ++n)                                                  \
      acc[m][n] =                                                                \
          __builtin_amdgcn_mfma_f32_32x32x16_bf16(AV[m], BV[n], acc[m][n], 0, 0, 0); \
  }                                                                              \
  __builtin_amdgcn_s_setprio(0)

// stage one ks-half (2 chunks) of A or B for the tile at running ptr rp
#define STAGE_A(rp, dA, ks)                                                      \
  GLDS((rp) + (ks) * 64,          (dA) + (ks) * 16384 + wv * 2048);              \
  GLDS((rp) + 131072 + (ks) * 64, (dA) + (ks) * 16384 + wv * 2048 + 1024)
#define STAGE_B(rp, dB, ks)                                                      \
  GLDS((rp) + (ks) * 64,          (dB) + (ks) * 16384 + wv * 2048);              \
  GLDS((rp) + 131072 + (ks) * 64, (dB) + (ks) * 16384 + wv * 2048 + 1024)

__global__ __launch_bounds__(512, 2) void gemm_k3(
    const unsigned short* __restrict__ Ah, const unsigned short* __restrict__ Al,
    const unsigned short* __restrict__ BhT, const unsigned short* __restrict__ BlT,
    float* __restrict__ C) {
  __shared__ __align__(16) char lds_[131072];  // 128 KiB

  const int tid = threadIdx.x;
  const int l   = tid & 63;
  const int wv  = tid >> 6;   // 0..7
  const int wm  = wv >> 2;    // 0..1
  const int wn  = wv & 3;     // 0..3
  const int j   = l & 31;     // frag row
  const int h   = l >> 5;     // frag k-granule half
  const int tt  = (j >> 1) & 3;

  // bijective XCD swizzle (256 blocks)
  const int bid = blockIdx.x;
  const int swz = (bid & 7) * 32 + (bid >> 3);
  const int bm = swz >> 4, bn = swz & 15;

  // ---- read lane bases (kappa=0); kappa=1 = base ^ 32 ----
  const int laneA0 = wm * 8192 + (j >> 4) * 1024 + (j & 15) * 64 + ((h ^ tt) * 16);
  const int laneB0 = 65536 + wn * 4096 + (j >> 4) * 1024 + (j & 15) * 64 + ((h ^ tt) * 16);
  const char* pa0 = lds_ + laneA0;
  const char* pa1 = lds_ + (laneA0 ^ 32);
  const char* pb0 = lds_ + laneB0;
  const char* pb1 = lds_ + (laneB0 ^ 32);

  // ---- staging lane source offset (bytes): row-in-unit l>>2, granule perm ----
  const size_t swz_src = (size_t)(l >> 2) * 8192 + (size_t)(((l & 3) ^ ((l >> 3) & 3))) * 16;
  const size_t src_lane = (size_t)wv * 262144 + swz_src;  // wave covers rows [wv*32, +32)

  const char* cAh = (const char*)Ah;
  const char* cAl = (const char*)Al;
  const char* cBh = (const char*)BhT;
  const char* cBl = (const char*)BlT;
  const size_t aoff = (size_t)(bm * 256) * 8192;
  const size_t boff = (size_t)(bn * 256) * 8192;

  f32x16 acc[4][2] = {};
  s16x8 aX[4], aY[4], bX[2], bY[2];

  // ---- prologue: stage tile 0 fully (A0,B0,A1,B1), drain, read slice0 ----
  {
    const char* rA = cAh + aoff + src_lane;
    const char* rB = cBh + boff + src_lane;
    char* dA = lds_;
    char* dB = lds_ + 65536;
    STAGE_A(rA, dA, 0);
    STAGE_B(rB, dB, 0);
    STAGE_A(rA, dA, 1);
    STAGE_B(rB, dB, 1);
  }
  WAITVM0();
  BARRIER();
  RD_A(aX, pa0, 0, 0);
  RD_B(bX, pb0, 0, 0);

  const char* segAp[3] = {cAh, cAl, cAh};
  const char* segBp[3] = {cBh, cBh, cBl};
  int t = 0;
#pragma unroll 1
  for (int seg = 0; seg < 3; ++seg) {
    // running per-lane source pointers for tile Tn = t+1
    const char* rpA = segAp[seg] + aoff + src_lane + ((seg == 0) ? 128 : 0);
    const char* rpB = segBp[seg] + boff + src_lane + ((seg == 0) ? 128 : 0);
    const int tEnd = 64 * (seg + 1) - 1;  // t runs while Tn < 64*(seg+1)
#pragma unroll 1
    for (; t < tEnd; ++t) {
      const int cb  = (t & 1) * 32768;
      const int cb2 = cb ^ 32768;
      char* dA = lds_ + cb2;
      char* dB = dA + 65536;

      // ---- ph0: read slice1(t) -> Y; stage A-ks0(t+1); MFMA slice0 (X) ----
      RD_A(aY, pa1, cb, 0);
      RD_B(bY, pb1, cb, 0);
      STAGE_A(rpA, dA, 0);
      MFMA32(aX, bX);

      // ---- ph1: drain ks1(t); read slice2(t) -> X; stage B-ks0(t+1); MFMA slice1 (Y)
      WAITVM2();
      BARRIER();
      RD_A(aX, pa0, cb, 16384);
      RD_B(bX, pb0, cb, 16384);
      STAGE_B(rpB, dB, 0);
      MFMA32(aY, bY);

      // ---- ph2: read slice3(t) -> Y; stage A-ks1(t+1); MFMA slice2 (X) ----
      RD_A(aY, pa1, cb, 16384);
      RD_B(bY, pb1, cb, 16384);
      STAGE_A(rpA, dA, 1);
      MFMA32(aX, bX);

      // ---- ph3: drain ks0(t+1); read slice0(t+1) from next buf; stage B-ks1(t+1); MFMA slice3 (Y)
      WAITVM2();
      BARRIER();
      RD_A(aX, pa0, cb2, 0);
      RD_B(bX, pb0, cb2, 0);
      STAGE_B(rpB, dB, 1);
      MFMA32(aY, bY);

      rpA += 128;
      rpB += 128;
    }
  }

  // ---- peeled tail: t = NT-1 (no staging, no next-tile reads) ----
  {
    const int cb = ((NT - 1) & 1) * 32768;
    // ph0
    RD_A(aY, pa1, cb, 0);
    RD_B(bY, pb1, cb, 0);
    MFMA32(aX, bX);
    // ph1 — drain this tile's ks1 units
    WAITVM0();
    BARRIER();
    RD_A(aX, pa0, cb, 16384);
    RD_B(bX, pb0, cb, 16384);
    MFMA32(aY, bY);
    // ph2
    RD_A(aY, pa1, cb, 16384);
    RD_B(bY, pb1, cb, 16384);
    MFMA32(aX, bX);
    // ph3
    MFMA32(aY, bY);
  }

  // ---- epilogue: 32x32 C/D layout col=lane&31, row=(reg&3)+8*(reg>>2)+4*(lane>>5)
  float* Cp = C + (size_t)(bm * 256 + wm * 128) * NDIM + (bn * 256 + wn * 64);
#pragma unroll
  for (int m = 0; m < 4; ++m)
#pragma unroll
    for (int n = 0; n < 2; ++n)
#pragma unroll
      for (int r = 0; r < 16; ++r) {
        const int row = m * 32 + (r & 3) + 8 * (r >> 2) + 4 * h;
        Cp[(size_t)row * NDIM + n * 32 + j] = acc[m][n][r];
      }
}

// ---------------- fallback: plain fp32 tiled GEMM (ws too small) ----------------
__global__ __launch_bounds__(1024) void gemm_fp32_fallback(const float* __restrict__ A,
                                                           const float* __restrict__ B,
                                                           float* __restrict__ C) {
  __shared__ float As[32][33];
  __shared__ float Bs[32][33];
  int tx = threadIdx.x, ty = threadIdx.y;
  int row = blockIdx.y * 32 + ty, colg = blockIdx.x * 32 + tx;
  float acc = 0.f;
  for (int k0 = 0; k0 < KDIM; k0 += 32) {
    As[ty][tx] = A[(size_t)row * KDIM + k0 + tx];
    Bs[ty][tx] = B[(size_t)(k0 + ty) * NDIM + colg];
    __syncthreads();
#pragma unroll 8
    for (int kk = 0; kk < 32; ++kk) acc += As[ty][kk] * Bs[kk][tx];
    __syncthreads();
  }
  C[(size_t)row * NDIM + colg] = acc;
}

extern "C" void kernel_launch(void* const* d_in, const int* in_sizes, int n_in,
                              void* d_out, int out_size, void* d_ws, size_t ws_size,
                              hipStream_t stream) {
  const float* A = (const float*)d_in[0];
  const float* B = (const float*)d_in[1];
  float* C = (float*)d_out;

  const size_t elems = (size_t)MDIM * KDIM;
  const size_t need = 4 * elems * sizeof(unsigned short);  // 128 MB
  if (ws_size < need) {
    gemm_fp32_fallback<<<dim3(NDIM / 32, MDIM / 32), dim3(32, 32), 0, stream>>>(A, B, C);
    return;
  }

  unsigned short* Ah  = (unsigned short*)d_ws;
  unsigned short* Al  = Ah + elems;
  unsigned short* BhT = Al + elems;
  unsigned short* BlT = BhT + elems;

  split_a<<<(int)(elems / (256 * 4)), 256, 0, stream>>>(A, Ah, Al);
  split_bt<<<dim3(NDIM / 32, KDIM / 32), dim3(32, 8), 0, stream>>>(B, BhT, BlT);
  gemm_k3<<<dim3(256), dim3(512), 0, stream>>>(Ah, Al, BhT, BlT, C);
}

// Round 10
// 366.778 us; speedup vs baseline: 1.2221x; 1.0699x over previous
//
#include <hip/hip_runtime.h>
#include <hip/hip_bf16.h>
#include <stdint.h>

#define MDIM 4096
#define NDIM 4096
#define KDIM 4096
#define NT 192   // effective K = 12288 over 3 bf16 segments, BK = 64

typedef float f32x4 __attribute__((ext_vector_type(4)));
typedef short s16x8 __attribute__((ext_vector_type(8)));

__device__ __forceinline__ unsigned short f2bf(float x) {
  uint32_t u = __float_as_uint(x);
  uint32_t r = (u + 0x7fffu + ((u >> 16) & 1u)) >> 16;  // RNE
  return (unsigned short)r;
}
__device__ __forceinline__ float bf2f(unsigned short b) {
  return __uint_as_float(((uint32_t)b) << 16);
}

// ---------------- pre-pass 1: split A -> A_hi, A_lo (bf16 [M][K])
__global__ __launch_bounds__(256) void split_a(const float* __restrict__ A,
                                               unsigned short* __restrict__ hi,
                                               unsigned short* __restrict__ lo) {
  size_t i = ((size_t)blockIdx.x * 256 + threadIdx.x) * 4;
  float4 v = *(const float4*)(A + i);
  ushort4 h, l;
  h.x = f2bf(v.x); l.x = f2bf(v.x - bf2f(h.x));
  h.y = f2bf(v.y); l.y = f2bf(v.y - bf2f(h.y));
  h.z = f2bf(v.z); l.z = f2bf(v.z - bf2f(h.z));
  h.w = f2bf(v.w); l.w = f2bf(v.w - bf2f(h.w));
  *(ushort4*)(hi + i) = h;
  *(ushort4*)(lo + i) = l;
}

// ---------------- pre-pass 2: split + transpose B -> B_hiT, B_loT (bf16 [N][K])
__global__ __launch_bounds__(256) void split_bt(const float* __restrict__ B,
                                                unsigned short* __restrict__ hiT,
                                                unsigned short* __restrict__ loT) {
  __shared__ float tile[32][33];
  int n0 = blockIdx.x * 32, k0 = blockIdx.y * 32;
  int tx = threadIdx.x, ty = threadIdx.y;  // block (32,8)
#pragma unroll
  for (int i = 0; i < 32; i += 8)
    tile[ty + i][tx] = B[(size_t)(k0 + ty + i) * NDIM + n0 + tx];
  __syncthreads();
#pragma unroll
  for (int i = 0; i < 32; i += 8) {
    float x = tile[tx][ty + i];
    unsigned short h = f2bf(x);
    unsigned short l = f2bf(x - bf2f(h));
    size_t o = (size_t)(n0 + ty + i) * KDIM + k0 + tx;
    hiT[o] = h;
    loT[o] = l;
  }
}

// ---------------- main GEMM: 256x256, BK=64, 8 waves (2Mx4N), per-wave 128x64,
// 16x16x32 MFMA (r6 proven layout, 0 bank conflicts). Deepened schedule:
// stages shifted one phase earlier (ph3 stages tile t+2's A-ks0), vmcnt(4)
// drains at ph1/ph3, 6-8 loads outstanding. Running segment source pointers.
#define GLDS(gp, lp)                                              \
  __builtin_amdgcn_global_load_lds(                               \
      (const __attribute__((address_space(1))) void*)(gp),        \
      (__attribute__((address_space(3))) void*)(lp), 16, 0, 0)

#define BARRIER() asm volatile("s_barrier" ::: "memory")
#define WAITVM4() asm volatile("s_waitcnt vmcnt(4)" ::: "memory")
#define WAITVM6() asm volatile("s_waitcnt vmcnt(6)" ::: "memory")
#define WAITVM0() asm volatile("s_waitcnt vmcnt(0)" ::: "memory")

// stage one ks-half unit (2 GLDS) from running src ptr rp into tile dst
#define STAGE_U(rp, dst, ks)                                                     \
  GLDS((rp) + (ks) * 64,          (dst) + (ks) * 16384 + dstBase);               \
  GLDS((rp) + 131072 + (ks) * 64, (dst) + (ks) * 16384 + dstBase + 1024)

#define RD_A4(dst, p)                                                            \
  _Pragma("unroll")                                                              \
  for (int m = 0; m < 4; ++m) dst[m] = *(const s16x8*)((p) + m * 1024)
#define RD_B4(dst, p)                                                            \
  _Pragma("unroll")                                                              \
  for (int n = 0; n < 4; ++n) dst[n] = *(const s16x8*)((p) + n * 1024)

#define MFMA_CL(MB, AV, BV)                                                      \
  __builtin_amdgcn_s_setprio(1);                                                 \
  _Pragma("unroll")                                                              \
  for (int m = 0; m < 4; ++m) {                                                  \
    _Pragma("unroll")                                                            \
    for (int n = 0; n < 4; ++n)                                                  \
      acc[MB + m][n] =                                                           \
          __builtin_amdgcn_mfma_f32_16x16x32_bf16(AV[m], BV[n], acc[MB + m][n], 0, 0, 0); \
  }                                                                              \
  __builtin_amdgcn_s_setprio(0)

__global__ __launch_bounds__(512, 2) void gemm_k3(
    const unsigned short* __restrict__ Ah, const unsigned short* __restrict__ Al,
    const unsigned short* __restrict__ BhT, const unsigned short* __restrict__ BlT,
    float* __restrict__ C) {
  __shared__ __align__(16) char lds_[131072];  // 128 KiB ring-2

  const int tid = threadIdx.x;
  const int l   = tid & 63;
  const int wv  = tid >> 6;   // 0..7
  const int wm  = wv >> 2;    // 0..1
  const int wn  = wv & 3;     // 0..3
  const int fr  = l & 15;
  const int fq  = l >> 4;

  // bijective XCD swizzle (256 blocks)
  const int bid = blockIdx.x;
  const int swz = (bid & 7) * 32 + (bid >> 3);
  const int bm = swz >> 4, bn = swz & 15;

  // staging lane geometry (linear LDS dest; inverse-swizzled global src) [r6]
  const int lG     = (l & 7) ^ (l >> 3);
  const int g_radd = 2 * (l >> 3) + (lG >> 2);
  const int g_col  = (lG & 3) * 16;
  const int dstBase = wv * 2048;  // (wv*32 rows) * 64 B

  // per-lane source offsets (panel-relative, bytes)
  const size_t srcOff = (size_t)(wv * 32 + g_radd) * 8192 + g_col;

  // read lane geometry (swizzled ds_read; same involution) [r6]
  const int slot  = (((fr & 1) << 2) | fq) ^ ((fr >> 1) & 7);
  const int laneA = ((wm * 128 + fr) >> 1) * 128 + slot * 16;
  const int laneB = 65536 + ((wn * 64 + fr) >> 1) * 128 + slot * 16;

  const char* cAh = (const char*)Ah;
  const char* cAl = (const char*)Al;
  const char* cBh = (const char*)BhT;
  const char* cBl = (const char*)BlT;
  const size_t aoff = (size_t)(bm * 256) * 8192 + srcOff;
  const size_t boff = (size_t)(bn * 256) * 8192 + srcOff;

  f32x4 acc[8][4] = {};
  s16x8 aX[4], aY[4], b0[4], b1[4];

  // ---- prologue: stage A0(0),B0(0),A1(0),B1(0),A0(1); drain first 2 units ----
  {
    const char* rA0 = cAh + aoff;
    const char* rB0 = cBh + boff;
    char* dA = lds_;
    char* dB = lds_ + 65536;
    STAGE_U(rA0, dA, 0);            // A-ks0(0)
    STAGE_U(rB0, dB, 0);            // B-ks0(0)
    STAGE_U(rA0, dA, 1);            // A-ks1(0)
    STAGE_U(rB0, dB, 1);            // B-ks1(0)
    STAGE_U(rA0 + 128, lds_ + 32768, 0);  // A-ks0(1) -> buf1
  }
  WAITVM6();   // A0(0),B0(0) resident; 6 loads in flight
  BARRIER();
  RD_A4(aX, lds_ + laneA);
  RD_B4(b0, lds_ + laneB);

  const char* segA[3]  = {cAh, cAl, cAh};
  const char* segB[3]  = {cBh, cBh, cBl};
  const char* segA1[3] = {cAl, cAh, cAh};  // next segment's A base (for t+2)
  int t = 0;
#pragma unroll 1
  for (int seg = 0; seg < 3; ++seg) {
    const char* rpA = segA[seg] + aoff + ((seg == 0) ? 128 : 0);   // tile t+1
    const char* rpB = segB[seg] + boff + ((seg == 0) ? 128 : 0);
    const char* rpA2end = segA1[seg] + aoff;                       // t+2 at seg cross
    const int tEnd = 64 * (seg + 1) - 1;
#pragma unroll 1
    for (; t < tEnd; ++t) {
      const int cb  = (t & 1) * 32768;
      const int cb2 = cb ^ 32768;
      char* dA = lds_ + cb2;            // buf of tile t+1
      char* dB = dA + 65536;
      const char* pa  = lds_ + cb + laneA;
      const char* pb  = lds_ + cb + laneB;
      const char* pa2 = lds_ + cb2 + laneA;
      const char* pb2 = lds_ + cb2 + laneB;
      const char* rpA2 = (t == tEnd - 1) ? rpA2end : (rpA + 128);
      const bool pf2 = (t + 2) < NT;

      // ---- ph0: read c1 frags (m4-7, k0); stage B-ks0(t+1); MFMA c0 ----
      RD_A4(aY, pa + 4096);
      STAGE_U(rpB, dB, 0);
      MFMA_CL(0, aX, b0);

      // ---- ph1: drain ks1(t); read (m0-3,k1)+b(k1); stage A-ks1(t+1); MFMA c1
      WAITVM4();
      BARRIER();
      RD_A4(aX, pa + 16384);
      RD_B4(b1, pb + 16384);
      STAGE_U(rpA, dA, 1);
      MFMA_CL(4, aY, b0);

      // ---- ph2: read c3 frags (m4-7, k1); stage B-ks1(t+1); MFMA c2 ----
      RD_A4(aY, pa + 16384 + 4096);
      STAGE_U(rpB, dB, 1);
      MFMA_CL(0, aX, b1);

      // ---- ph3: drain ks0(t+1); read (m0-3,k0)+b(k0) of t+1; stage A-ks0(t+2); MFMA c3
      WAITVM4();
      BARRIER();
      RD_A4(aX, pa2);
      RD_B4(b0, pb2);
      if (pf2) { STAGE_U(rpA2, lds_ + cb, 0); }   // into buf[(t+2)&1] = cb
      MFMA_CL(4, aY, b1);

      rpA += 128;
      rpB += 128;
    }
  }

  // ---- peeled tail: t = NT-1 (no staging) ----
  {
    const int cb = ((NT - 1) & 1) * 32768;
    const char* pa = lds_ + cb + laneA;
    const char* pb = lds_ + cb + laneB;
    // ph0
    RD_A4(aY, pa + 4096);
    MFMA_CL(0, aX, b0);
    // ph1 — drain this tile's ks1 units
    WAITVM0();
    BARRIER();
    RD_A4(aX, pa + 16384);
    RD_B4(b1, pb + 16384);
    MFMA_CL(4, aY, b0);
    // ph2
    RD_A4(aY, pa + 16384 + 4096);
    MFMA_CL(0, aX, b1);
    // ph3
    MFMA_CL(4, aY, b1);
  }

  // ---- epilogue: C/D layout col=lane&15, row=(lane>>4)*4+j [r6 verified] ----
  float* Cp = C + (size_t)(bm * 256 + wm * 128) * NDIM + (bn * 256 + wn * 64);
#pragma unroll
  for (int m = 0; m < 8; ++m)
#pragma unroll
    for (int n = 0; n < 4; ++n)
#pragma unroll
      for (int j = 0; j < 4; ++j)
        Cp[(size_t)(m * 16 + fq * 4 + j) * NDIM + n * 16 + fr] = acc[m][n][j];
}

// ---------------- fallback: plain fp32 tiled GEMM (ws too small) ----------------
__global__ __launch_bounds__(1024) void gemm_fp32_fallback(const float* __restrict__ A,
                                                           const float* __restrict__ B,
                                                           float* __restrict__ C) {
  __shared__ float As[32][33];
  __shared__ float Bs[32][33];
  int tx = threadIdx.x, ty = threadIdx.y;
  int row = blockIdx.y * 32 + ty, colg = blockIdx.x * 32 + tx;
  float acc = 0.f;
  for (int k0 = 0; k0 < KDIM; k0 += 32) {
    As[ty][tx] = A[(size_t)row * KDIM + k0 + tx];
    Bs[ty][tx] = B[(size_t)(k0 + ty) * NDIM + colg];
    __syncthreads();
#pragma unroll 8
    for (int kk = 0; kk < 32; ++kk) acc += As[ty][kk] * Bs[kk][tx];
    __syncthreads();
  }
  C[(size_t)row * NDIM + colg] = acc;
}

extern "C" void kernel_launch(void* const* d_in, const int* in_sizes, int n_in,
                              void* d_out, int out_size, void* d_ws, size_t ws_size,
                              hipStream_t stream) {
  const float* A = (const float*)d_in[0];
  const float* B = (const float*)d_in[1];
  float* C = (float*)d_out;

  const size_t elems = (size_t)MDIM * KDIM;
  const size_t need = 4 * elems * sizeof(unsigned short);  // 128 MB
  if (ws_size < need) {
    gemm_fp32_fallback<<<dim3(NDIM / 32, MDIM / 32), dim3(32, 32), 0, stream>>>(A, B, C);
    return;
  }

  unsigned short* Ah  = (unsigned short*)d_ws;
  unsigned short* Al  = Ah + elems;
  unsigned short* BhT = Al + elems;
  unsigned short* BlT = BhT + elems;

  split_a<<<(int)(elems / (256 * 4)), 256, 0, stream>>>(A, Ah, Al);
  split_bt<<<dim3(NDIM / 32, KDIM / 32), dim3(32, 8), 0, stream>>>(B, BhT, BlT);
  gemm_k3<<<dim3(256), dim3(512), 0, stream>>>(Ah, Al, BhT, BlT, C);
}